// Round 1
// baseline (1668.181 us; speedup 1.0000x reference)
//
#include <hip/hip_runtime.h>
#include <math.h>

#define NUSERS 50000
#define NITEMS 50000
#define NTOT   100000
#define MPAD   100032   // 6252 tiles of 16 rows, divisible by 64
#define KDIM   512

typedef __attribute__((ext_vector_type(4))) float f32x4;
typedef __attribute__((ext_vector_type(8))) short short8;

static __device__ __forceinline__ unsigned short f2bf(float f) {
  unsigned int u = __float_as_uint(f);
  u += 0x7fffu + ((u >> 16) & 1u);
  return (unsigned short)(u >> 16);
}

// Build packed 512x512 bf16 weight and 512 bias:
// gates layout over columns g: [0,128)=r_sum, [128,256)=z_sum, [256,384)=i_n, [384,512)=h_n
// input layout over k: [0,384)=x (mean mail), [384,512)=h
__global__ void pack_w_kernel(const float* __restrict__ w_ih,
                              const float* __restrict__ w_hh,
                              const float* __restrict__ b_ih,
                              const float* __restrict__ b_hh,
                              unsigned short* __restrict__ Wb,
                              float* __restrict__ bb) {
  int idx = blockIdx.x * 256 + threadIdx.x;   // 0 .. 512*512-1
  int g = idx >> 9, k = idx & 511;
  float v;
  if (g < 256)      v = (k < 384) ? w_ih[g*384 + k] : w_hh[g*128 + (k-384)];
  else if (g < 384) v = (k < 384) ? w_ih[g*384 + k] : 0.0f;
  else              v = (k < 384) ? 0.0f : w_hh[(g-128)*128 + (k-384)];
  Wb[idx] = f2bf(v);
  if (idx < 512) {
    float b = (idx < 256) ? (b_ih[idx] + b_hh[idx])
            : (idx < 384) ? b_ih[idx]
                          : b_hh[idx - 128];
    bb[idx] = b;
  }
}

// One block (256 threads) per edge. Accumulates 256 components:
// [0,128)=src_mem[src], [128,192)=cos(t*freq), [192,256)=edge feat
__global__ void scatter_kernel(const float* __restrict__ smem,
                               const float* __restrict__ ts,
                               const float* __restrict__ ef,
                               const int* __restrict__ src,
                               const int* __restrict__ dst,
                               float* __restrict__ acc,
                               float* __restrict__ cnt) {
  int e = blockIdx.x;
  int c = threadIdx.x;
  int s = src[e];
  int d = dst[e];
  float v;
  if (c < 128) {
    v = smem[(size_t)s * 128 + c];
  } else if (c < 192) {
    // freq[j] = 10^(-9j/63) = exp(-(j/7)*ln(10))
    float freq = expf((float)(c - 128) * (-0.14285714285714285f) * 2.302585092994046f);
    v = cosf(ts[e] * freq);
  } else {
    v = ef[(size_t)e * 64 + (c - 192)];
  }
  atomicAdd(&acc[(size_t)d * 256 + c], v);
  if (c == 0) atomicAdd(&cnt[d], 1.0f);
}

// Build X' (MPAD x 512 bf16): [0,128)=acc_src/c, [128,256)=h*(cnt>0),
// [256,384)=acc_{tenc,e}/c, [384,512)=h.  Rows 0..49999 users, 50000..99999 items.
__global__ void pack_x_kernel(const float* __restrict__ acc_i,
                              const float* __restrict__ acc_j,
                              const float* __restrict__ cnt_i,
                              const float* __restrict__ cnt_j,
                              const float* __restrict__ sj_r,
                              const float* __restrict__ sj,
                              unsigned short* __restrict__ Xb) {
  int row = blockIdx.x;
  int k = threadIdx.x;
  size_t o = (size_t)row * KDIM + k;
  if (row >= NTOT) { Xb[o] = 0; return; }
  bool user = row < NUSERS;
  int node = user ? row : row - NUSERS;
  const float* acc = user ? acc_i : acc_j;
  float c = (user ? cnt_i : cnt_j)[node];
  const float* h = user ? sj_r : sj;
  float invc = 1.0f / fmaxf(c, 1.0f);
  float v;
  if (k < 128)      v = acc[(size_t)node * 256 + k] * invc;
  else if (k < 256) v = (c > 0.0f) ? h[(size_t)node * 128 + (k - 128)] : 0.0f;
  else if (k < 384) v = acc[(size_t)node * 256 + (k - 128)] * invc;
  else              v = h[(size_t)node * 128 + (k - 384)];
  Xb[o] = f2bf(v);
}

// GEMM (MPAD x 512) @ (512 x 512)^T-ish with fused GRU epilogue.
// One wave: 16 rows x all 512 gate-cols (32 accumulators). Block = 4 waves.
__global__ __launch_bounds__(256) void gemm_gru_kernel(
    const unsigned short* __restrict__ Xb,
    const unsigned short* __restrict__ Wb,
    const float* __restrict__ bb,
    const float* __restrict__ sj_r,
    const float* __restrict__ sj,
    float* __restrict__ out) {
  int wid = threadIdx.x >> 6, lane = threadIdx.x & 63;
  int mtile = blockIdx.x * 4 + wid;
  int m0 = mtile * 16;
  int col16 = lane & 15, quad = lane >> 4;
  int koff = quad * 8;

  f32x4 acc[32];
#pragma unroll
  for (int t = 0; t < 32; ++t) acc[t] = (f32x4)0.0f;

  const unsigned short* arow = Xb + (size_t)(m0 + col16) * KDIM + koff;
  const unsigned short* brow = Wb + (size_t)col16 * KDIM + koff;

  for (int kt = 0; kt < 16; ++kt) {
    short8 a = *(const short8*)(arow + kt * 32);
#pragma unroll
    for (int t = 0; t < 32; ++t) {
      short8 b = *(const short8*)(brow + (size_t)t * 16 * KDIM + kt * 32);
      acc[t] = __builtin_amdgcn_mfma_f32_16x16x32_bf16(a, b, acc[t], 0, 0, 0);
    }
  }

  // Epilogue: lane holds D[row=quad*4+r][col=col16] per 16-col tile t.
  // c = t*16+col16: r_pre=acc[t], z_pre=acc[t+8], i_n=acc[t+16], h_n=acc[t+24]
#pragma unroll
  for (int t = 0; t < 8; ++t) {
    int c = t * 16 + col16;
    float bbr = bb[c], bbz = bb[128 + c], bbn = bb[256 + c], bbh = bb[384 + c];
#pragma unroll
    for (int r = 0; r < 4; ++r) {
      int row = m0 + quad * 4 + r;
      if (row < NTOT) {
        float rp  = acc[t][r]      + bbr;
        float zp  = acc[t + 8][r]  + bbz;
        float inp = acc[t + 16][r] + bbn;
        float hnp = acc[t + 24][r] + bbh;
        float rg = 1.0f / (1.0f + expf(-rp));
        float zg = 1.0f / (1.0f + expf(-zp));
        float ng = tanhf(inp + rg * hnp);
        float hv = (row < NUSERS) ? sj_r[(size_t)row * 128 + c]
                                  : sj[(size_t)(row - NUSERS) * 128 + c];
        out[(size_t)row * 128 + c] = (1.0f - zg) * ng + zg * hv;
      }
    }
  }
}

extern "C" void kernel_launch(void* const* d_in, const int* in_sizes, int n_in,
                              void* d_out, int out_size, void* d_ws, size_t ws_size,
                              hipStream_t stream) {
  const float* si   = (const float*)d_in[0];
  const float* sj   = (const float*)d_in[1];
  const float* si_r = (const float*)d_in[2];
  const float* sj_r = (const float*)d_in[3];
  const float* t    = (const float*)d_in[4];
  const float* t_r  = (const float*)d_in[5];
  const float* e    = (const float*)d_in[6];
  const float* e_r  = (const float*)d_in[7];
  const float* w_ih = (const float*)d_in[8];
  const float* w_hh = (const float*)d_in[9];
  const float* b_ih = (const float*)d_in[10];
  const float* b_hh = (const float*)d_in[11];
  const int* src_g  = (const int*)d_in[12];
  const int* dst_g  = (const int*)d_in[13];
  const int* src_gr = (const int*)d_in[14];
  const int* dst_gr = (const int*)d_in[15];
  int E = in_sizes[4];

  float* ws = (float*)d_ws;
  float* acc_j = ws;                                  // NITEMS*256 f32
  float* acc_i = acc_j + (size_t)NITEMS * 256;        // NUSERS*256 f32
  float* cnt_j = acc_i + (size_t)NUSERS * 256;        // NITEMS f32
  float* cnt_i = cnt_j + NITEMS;                      // NUSERS f32
  float* bb    = cnt_i + NUSERS;                      // 512 f32
  unsigned short* Wb = (unsigned short*)(bb + 512);   // 512*512 bf16
  unsigned short* Xb = Wb + (size_t)512 * 512;        // MPAD*512 bf16

  size_t zero_bytes =
      ((size_t)NITEMS * 256 + (size_t)NUSERS * 256 + NITEMS + NUSERS) * sizeof(float);
  hipMemsetAsync(d_ws, 0, zero_bytes, stream);

  pack_w_kernel<<<(512 * 512) / 256, 256, 0, stream>>>(w_ih, w_hh, b_ih, b_hh, Wb, bb);

  scatter_kernel<<<E, 256, 0, stream>>>(si,   t,   e,   src_g,  dst_g,  acc_j, cnt_j);
  scatter_kernel<<<E, 256, 0, stream>>>(si_r, t_r, e_r, src_gr, dst_gr, acc_i, cnt_i);

  pack_x_kernel<<<MPAD, 512, 0, stream>>>(acc_i, acc_j, cnt_i, cnt_j, sj_r, sj, Xb);

  float* out = (float*)d_out;   // si_out (50000x128) || sj_out (50000x128)
  gemm_gru_kernel<<<MPAD / 64, 256, 0, stream>>>(Xb, Wb, bb, sj_r, sj, out);
}

// Round 2
// 720.602 us; speedup vs baseline: 2.3150x; 2.3150x over previous
//
#include <hip/hip_runtime.h>
#include <math.h>

#define NUSERS 50000
#define NITEMS 50000
#define NTOT   100000
#define NNODE  50000      // per direction
#define NCHUNK 196        // ceil(50000/256)
#define MTILES 6250       // 100000/16 row tiles
#define KDIM   512

typedef __attribute__((ext_vector_type(4))) float f32x4;
typedef __attribute__((ext_vector_type(8))) short short8;
typedef unsigned int u32;

#define AS1 __attribute__((address_space(1)))
#define AS3 __attribute__((address_space(3)))

static __device__ __forceinline__ unsigned short f2bf(float f) {
  unsigned int u = __float_as_uint(f);
  u += 0x7fffu + ((u >> 16) & 1u);
  return (unsigned short)(u >> 16);
}

static __device__ __forceinline__ void gload_lds16(const void* g, void* l) {
  __builtin_amdgcn_global_load_lds((const AS1 u32*)g, (AS3 u32*)l, 16, 0, 0);
}

// ---------------- pack W'' into MFMA B-fragment order -----------------
// W'' gates g: [0,128)=r_sum [128,256)=z_sum [256,384)=i_n [384,512)=h_n
// k: [0,384)=x, [384,512)=h.
// frag idx = ((t*16 + kt)*64 + lane)*8 + j  holds W''[t*16+(lane&15)][kt*32+(lane>>4)*8+j]
__global__ void pack_w_kernel(const float* __restrict__ w_ih,
                              const float* __restrict__ w_hh,
                              const float* __restrict__ b_ih,
                              const float* __restrict__ b_hh,
                              unsigned short* __restrict__ Wb,
                              float* __restrict__ bb) {
  int idx = blockIdx.x * 256 + threadIdx.x;       // 0 .. 512*512-1
  int j = idx & 7, l = (idx >> 3) & 63, ktt = idx >> 9;
  int kt = ktt & 15, tt = ktt >> 4;
  int g = tt * 16 + (l & 15);
  int k = kt * 32 + (l >> 4) * 8 + j;
  float v;
  if (g < 256)      v = (k < 384) ? w_ih[g * 384 + k] : w_hh[g * 128 + (k - 384)];
  else if (g < 384) v = (k < 384) ? w_ih[g * 384 + k] : 0.0f;
  else              v = (k < 384) ? 0.0f : w_hh[(g - 128) * 128 + (k - 384)];
  Wb[idx] = f2bf(v);
  if (idx < 512) {
    float b = (idx < 256) ? (b_ih[idx] + b_hh[idx])
            : (idx < 384) ? b_ih[idx]
                          : b_hh[idx - 128];
    bb[idx] = b;
  }
}

// ---------------- CSR build -----------------
__global__ void hist_kernel(const int* __restrict__ dst_g,
                            const int* __restrict__ dst_gr,
                            int* __restrict__ deg_j, int* __restrict__ deg_i, int E) {
  int i = blockIdx.x * 256 + threadIdx.x;
  if (i < E) atomicAdd(&deg_j[dst_g[i]], 1);
  else if (i < 2 * E) atomicAdd(&deg_i[dst_gr[i - E]], 1);
}

__global__ void chunksum_kernel(const int* __restrict__ deg_j,
                                const int* __restrict__ deg_i,
                                int* __restrict__ csum) {
  int c = blockIdx.x;                    // 0..2*NCHUNK-1
  const int* deg = (c < NCHUNK) ? deg_j : deg_i;
  int cc = (c < NCHUNK) ? c : c - NCHUNK;
  int t = threadIdx.x;
  int idx = cc * 256 + t;
  int v = (idx < NNODE) ? deg[idx] : 0;
  for (int off = 32; off; off >>= 1) v += __shfl_down(v, off, 64);
  __shared__ int wsum[4];
  if ((t & 63) == 0) wsum[t >> 6] = v;
  __syncthreads();
  if (t == 0) csum[c] = wsum[0] + wsum[1] + wsum[2] + wsum[3];
}

__global__ void chunkscan_kernel(const int* __restrict__ csum, int* __restrict__ coff) {
  int d = blockIdx.x;                    // 0 or 1
  const int* cs = csum + d * NCHUNK;
  int* co = coff + d * NCHUNK;
  int t = threadIdx.x, lane = t & 63, w = t >> 6;
  int v = (t < NCHUNK) ? cs[t] : 0;
  int x = v;
  for (int off = 1; off < 64; off <<= 1) {
    int y = __shfl_up(x, off, 64);
    if (lane >= off) x += y;
  }
  __shared__ int wt[4];
  if (lane == 63) wt[w] = x;
  __syncthreads();
  int add = 0;
  for (int k = 0; k < 4; ++k) if (k < w) add += wt[k];
  if (t < NCHUNK) co[t] = add + x - v;   // exclusive prefix
}

__global__ void localscan_kernel(const int* __restrict__ deg_j,
                                 const int* __restrict__ deg_i,
                                 const int* __restrict__ coff,
                                 int* __restrict__ rs_j, int* __restrict__ cur_j,
                                 int* __restrict__ rs_i, int* __restrict__ cur_i) {
  int c = blockIdx.x;
  bool dj = c < NCHUNK;
  const int* deg = dj ? deg_j : deg_i;
  int cc = dj ? c : c - NCHUNK;
  int* rs = dj ? rs_j : rs_i;
  int* cur = dj ? cur_j : cur_i;
  int base = coff[c];
  int t = threadIdx.x, lane = t & 63, w = t >> 6;
  int idx = cc * 256 + t;
  int v = (idx < NNODE) ? deg[idx] : 0;
  int x = v;
  for (int off = 1; off < 64; off <<= 1) {
    int y = __shfl_up(x, off, 64);
    if (lane >= off) x += y;
  }
  __shared__ int wt[4];
  if (lane == 63) wt[w] = x;
  __syncthreads();
  int add = 0;
  for (int k = 0; k < 4; ++k) if (k < w) add += wt[k];
  int ex = base + add + x - v;
  if (idx < NNODE) { rs[idx] = ex; cur[idx] = ex; }
}

__global__ void fill_kernel(const int* __restrict__ src_g, const int* __restrict__ dst_g,
                            const float* __restrict__ t,
                            const int* __restrict__ src_gr, const int* __restrict__ dst_gr,
                            const float* __restrict__ t_r,
                            int* __restrict__ cur_j, int* __restrict__ cur_i,
                            int* __restrict__ srcP_j, float* __restrict__ tsP_j, int* __restrict__ eidP_j,
                            int* __restrict__ srcP_i, float* __restrict__ tsP_i, int* __restrict__ eidP_i,
                            int E) {
  int i = blockIdx.x * 256 + threadIdx.x;
  if (i < E) {
    int pos = atomicAdd(&cur_j[dst_g[i]], 1);
    srcP_j[pos] = src_g[i]; tsP_j[pos] = t[i]; eidP_j[pos] = i;
  } else if (i < 2 * E) {
    int k = i - E;
    int pos = atomicAdd(&cur_i[dst_gr[k]], 1);
    srcP_i[pos] = src_gr[k]; tsP_i[pos] = t_r[k]; eidP_i[pos] = k;
  }
}

// ---------------- gather: mean-message + pack X row in A-fragment order ----------------
// packed k layout: [0,128)=mean src_mem, [128,256)=h*(deg>0), [256,320)=mean tenc,
// [320,384)=mean edge feat, [384,512)=h
__global__ __launch_bounds__(256) void gather_kernel(
    const float* __restrict__ si, const float* __restrict__ sj,
    const float* __restrict__ si_r, const float* __restrict__ sj_r,
    const float* __restrict__ e, const float* __restrict__ e_r,
    const int* __restrict__ rs_j, const int* __restrict__ rs_i,
    const int* __restrict__ deg_j, const int* __restrict__ deg_i,
    const int* __restrict__ srcP_j, const float* __restrict__ tsP_j, const int* __restrict__ eidP_j,
    const int* __restrict__ srcP_i, const float* __restrict__ tsP_i, const int* __restrict__ eidP_i,
    unsigned short* __restrict__ Xb) {
  __shared__ __align__(16) unsigned short rowbuf[4][512];
  int wid = threadIdx.x >> 6, lane = threadIdx.x & 63;
  int node = blockIdx.x * 4 + wid;                 // 0..99999
  bool user = node < NUSERS;
  int idx = user ? node : node - NUSERS;
  const float* smem = user ? si_r : si;
  const float* h    = user ? sj_r : sj;
  const float* ef   = user ? e_r : e;
  int start = (user ? rs_i : rs_j)[idx];
  int deg   = (user ? deg_i : deg_j)[idx];
  const int*   srcP = user ? srcP_i : srcP_j;
  const float* tsP  = user ? tsP_i : tsP_j;
  const int*   eidP = user ? eidP_i : eidP_j;

  // freq[lane] = 10^(-9*lane/63) = exp(-lane * 9/63 * ln 10)
  float freq = __expf((float)lane * -0.3289407276f);
  float a0 = 0.f, a1 = 0.f, a2 = 0.f, a3 = 0.f;
  for (int i = 0; i < deg; ++i) {
    int p = start + i;
    int s = srcP[p];
    float tv = tsP[p];
    int eid = eidP[p];
    a0 += smem[(size_t)s * 128 + lane];
    a1 += smem[(size_t)s * 128 + 64 + lane];
    a2 += __cosf(tv * freq);
    a3 += ef[(size_t)eid * 64 + lane];
  }
  float invc = (deg > 0) ? 1.0f / (float)deg : 0.0f;
  float hz   = (deg > 0) ? 1.0f : 0.0f;
  float h0 = h[(size_t)idx * 128 + lane];
  float h1 = h[(size_t)idx * 128 + 64 + lane];

  unsigned short* rb = rowbuf[wid];
  rb[lane]        = f2bf(a0 * invc);
  rb[64  + lane]  = f2bf(a1 * invc);
  rb[128 + lane]  = f2bf(h0 * hz);
  rb[192 + lane]  = f2bf(h1 * hz);
  rb[256 + lane]  = f2bf(a2 * invc);
  rb[320 + lane]  = f2bf(a3 * invc);
  rb[384 + lane]  = f2bf(h0);
  rb[448 + lane]  = f2bf(h1);
  __syncthreads();

  // transpose-write in A-fragment order: lane owns k = lane*8 .. lane*8+8
  int rt = node >> 4, m = node & 15;
  int kt = lane >> 2, q = lane & 3;
  short8 vv = *(const short8*)(rb + lane * 8);
  *(short8*)(Xb + (((size_t)rt * 16 + kt) * 64 + q * 16 + m) * 8) = vv;
}

// ---------------- GEMM (100000 x 512) @ W''^T with fused GRU epilogue ----------------
// 512 threads = 8 waves, 16 rows/wave -> 128 rows/block. B staged in LDS in 8 slabs of
// 64KB (2 k-tiles x 32 col-tiles) via global_load_lds; A read coalesced from global
// (fragment order). Epilogue applies biases + GRU and writes f32 output.
__global__ __launch_bounds__(512, 2) void gemm_gru_kernel(
    const unsigned short* __restrict__ Xb,
    const unsigned short* __restrict__ Wb,
    const float* __restrict__ bb,
    const float* __restrict__ sj_r,
    const float* __restrict__ sj,
    float* __restrict__ out) {
  __shared__ __align__(16) unsigned short sB[32768];   // 64 KB
  int wid = threadIdx.x >> 6, lane = threadIdx.x & 63;
  int mtile = blockIdx.x * 8 + wid;
  bool valid = mtile < MTILES;
  int col16 = lane & 15, quad = lane >> 4;

  f32x4 acc[32];
#pragma unroll
  for (int t = 0; t < 32; ++t) acc[t] = (f32x4)0.0f;

  const unsigned short* Abase = Xb + (size_t)(valid ? mtile : 0) * 8192;

  for (int s = 0; s < 8; ++s) {
    // stage slab s: chunks c=0..63, chunk c <-> (t=c>>1, kt=2s+(c&1)), 1KB each
#pragma unroll
    for (int i = 0; i < 8; ++i) {
      int c = wid * 8 + i;
      int tt = c >> 1, kt = s * 2 + (c & 1);
      const unsigned short* g = Wb + ((size_t)(tt * 16 + kt) * 64 + lane) * 8;
      gload_lds16(g, sB + c * 512);
    }
    __syncthreads();
    if (valid) {
      short8 a0 = *(const short8*)(Abase + (size_t)(s * 2) * 512 + lane * 8);
      short8 a1 = *(const short8*)(Abase + (size_t)(s * 2 + 1) * 512 + lane * 8);
#pragma unroll
      for (int t = 0; t < 32; ++t) {
        short8 b0 = *(const short8*)(sB + (t * 2) * 512 + lane * 8);
        short8 b1 = *(const short8*)(sB + (t * 2 + 1) * 512 + lane * 8);
        acc[t] = __builtin_amdgcn_mfma_f32_16x16x32_bf16(a0, b0, acc[t], 0, 0, 0);
        acc[t] = __builtin_amdgcn_mfma_f32_16x16x32_bf16(a1, b1, acc[t], 0, 0, 0);
      }
    }
    __syncthreads();
  }

  if (!valid) return;
  int m0 = mtile * 16;
#pragma unroll
  for (int t = 0; t < 8; ++t) {
    int c = t * 16 + col16;
    float bbr = bb[c], bbz = bb[128 + c], bbn = bb[256 + c], bbh = bb[384 + c];
#pragma unroll
    for (int r = 0; r < 4; ++r) {
      int row = m0 + quad * 4 + r;
      float rp  = acc[t][r]      + bbr;
      float zp  = acc[t + 8][r]  + bbz;
      float inp = acc[t + 16][r] + bbn;
      float hnp = acc[t + 24][r] + bbh;
      float rg = 1.0f / (1.0f + __expf(-rp));
      float zg = 1.0f / (1.0f + __expf(-zp));
      float ng = tanhf(inp + rg * hnp);
      float hv = (row < NUSERS) ? sj_r[(size_t)row * 128 + c]
                                : sj[(size_t)(row - NUSERS) * 128 + c];
      out[(size_t)row * 128 + c] = (1.0f - zg) * ng + zg * hv;
    }
  }
}

extern "C" void kernel_launch(void* const* d_in, const int* in_sizes, int n_in,
                              void* d_out, int out_size, void* d_ws, size_t ws_size,
                              hipStream_t stream) {
  const float* si   = (const float*)d_in[0];
  const float* sj   = (const float*)d_in[1];
  const float* si_r = (const float*)d_in[2];
  const float* sj_r = (const float*)d_in[3];
  const float* t    = (const float*)d_in[4];
  const float* t_r  = (const float*)d_in[5];
  const float* e    = (const float*)d_in[6];
  const float* e_r  = (const float*)d_in[7];
  const float* w_ih = (const float*)d_in[8];
  const float* w_hh = (const float*)d_in[9];
  const float* b_ih = (const float*)d_in[10];
  const float* b_hh = (const float*)d_in[11];
  const int* src_g  = (const int*)d_in[12];
  const int* dst_g  = (const int*)d_in[13];
  const int* src_gr = (const int*)d_in[14];
  const int* dst_gr = (const int*)d_in[15];
  int E = in_sizes[4];

  // workspace layout (16B-aligned head first)
  unsigned short* Xb = (unsigned short*)d_ws;          // 51,200,000 shorts (102.4 MB)
  unsigned short* Wb = Xb + (size_t)MTILES * 8192;     // 262144 shorts
  float* bb   = (float*)(Wb + 262144);                 // 512
  int* deg_j  = (int*)(bb + 512);                      // 50000  (memset target, with deg_i)
  int* deg_i  = deg_j + NNODE;                         // 50000
  int* rs_j   = deg_i + NNODE;                         // 50000
  int* rs_i   = rs_j + NNODE;                          // 50000
  int* cur_j  = rs_i + NNODE;                          // 50000
  int* cur_i  = cur_j + NNODE;                         // 50000
  int* csum   = cur_i + NNODE;                         // 2*NCHUNK
  int* coff   = csum + 2 * NCHUNK;                     // 2*NCHUNK
  int* srcP_j = coff + 2 * NCHUNK;                     // E
  int* eidP_j = srcP_j + E;                            // E
  float* tsP_j = (float*)(eidP_j + E);                 // E
  int* srcP_i = (int*)(tsP_j + E);                     // E
  int* eidP_i = srcP_i + E;                            // E
  float* tsP_i = (float*)(eidP_i + E);                 // E

  hipMemsetAsync(deg_j, 0, 2 * NNODE * sizeof(int), stream);

  pack_w_kernel<<<(512 * 512) / 256, 256, 0, stream>>>(w_ih, w_hh, b_ih, b_hh, Wb, bb);

  int blks2E = (2 * E + 255) / 256;
  hist_kernel<<<blks2E, 256, 0, stream>>>(dst_g, dst_gr, deg_j, deg_i, E);
  chunksum_kernel<<<2 * NCHUNK, 256, 0, stream>>>(deg_j, deg_i, csum);
  chunkscan_kernel<<<2, 256, 0, stream>>>(csum, coff);
  localscan_kernel<<<2 * NCHUNK, 256, 0, stream>>>(deg_j, deg_i, coff, rs_j, cur_j, rs_i, cur_i);
  fill_kernel<<<blks2E, 256, 0, stream>>>(src_g, dst_g, t, src_gr, dst_gr, t_r,
                                          cur_j, cur_i,
                                          srcP_j, tsP_j, eidP_j,
                                          srcP_i, tsP_i, eidP_i, E);

  gather_kernel<<<NTOT / 4, 256, 0, stream>>>(si, sj, si_r, sj_r, e, e_r,
                                              rs_j, rs_i, deg_j, deg_i,
                                              srcP_j, tsP_j, eidP_j,
                                              srcP_i, tsP_i, eidP_i, Xb);

  float* out = (float*)d_out;
  gemm_gru_kernel<<<(MTILES + 7) / 8, 512, 0, stream>>>(Xb, Wb, bb, sj_r, sj, out);
}

// Round 3
// 656.852 us; speedup vs baseline: 2.5397x; 1.0971x over previous
//
#include <hip/hip_runtime.h>
#include <math.h>

#define NUSERS 50000
#define NITEMS 50000
#define NTOT   100000
#define NNODE  50000      // per direction
#define NCHUNK 196        // ceil(50000/256)
#define MTILES 6250       // 100000/16 row tiles
#define KDIM   512

typedef __attribute__((ext_vector_type(4))) float f32x4;
typedef __attribute__((ext_vector_type(8))) short short8;
typedef unsigned int u32;

#define AS1 __attribute__((address_space(1)))
#define AS3 __attribute__((address_space(3)))

static __device__ __forceinline__ unsigned short f2bf(float f) {
  unsigned int u = __float_as_uint(f);
  u += 0x7fffu + ((u >> 16) & 1u);
  return (unsigned short)(u >> 16);
}

static __device__ __forceinline__ void gload_lds16(const void* g, void* l) {
  __builtin_amdgcn_global_load_lds((const AS1 u32*)g, (AS3 u32*)l, 16, 0, 0);
}

// ---------------- pack W'' into MFMA B-fragment order -----------------
__global__ void pack_w_kernel(const float* __restrict__ w_ih,
                              const float* __restrict__ w_hh,
                              const float* __restrict__ b_ih,
                              const float* __restrict__ b_hh,
                              unsigned short* __restrict__ Wb,
                              float* __restrict__ bb) {
  int idx = blockIdx.x * 256 + threadIdx.x;       // 0 .. 512*512-1
  int j = idx & 7, l = (idx >> 3) & 63, ktt = idx >> 9;
  int kt = ktt & 15, tt = ktt >> 4;
  int g = tt * 16 + (l & 15);
  int k = kt * 32 + (l >> 4) * 8 + j;
  float v;
  if (g < 256)      v = (k < 384) ? w_ih[g * 384 + k] : w_hh[g * 128 + (k - 384)];
  else if (g < 384) v = (k < 384) ? w_ih[g * 384 + k] : 0.0f;
  else              v = (k < 384) ? 0.0f : w_hh[(g - 128) * 128 + (k - 384)];
  Wb[idx] = f2bf(v);
  if (idx < 512) {
    float b = (idx < 256) ? (b_ih[idx] + b_hh[idx])
            : (idx < 384) ? b_ih[idx]
                          : b_hh[idx - 128];
    bb[idx] = b;
  }
}

// ---------------- CSR build -----------------
__global__ void hist_kernel(const int* __restrict__ dst_g,
                            const int* __restrict__ dst_gr,
                            int* __restrict__ deg_j, int* __restrict__ deg_i, int E) {
  int i = blockIdx.x * 256 + threadIdx.x;
  if (i < E) atomicAdd(&deg_j[dst_g[i]], 1);
  else if (i < 2 * E) atomicAdd(&deg_i[dst_gr[i - E]], 1);
}

__global__ void chunksum_kernel(const int* __restrict__ deg_j,
                                const int* __restrict__ deg_i,
                                int* __restrict__ csum) {
  int c = blockIdx.x;                    // 0..2*NCHUNK-1
  const int* deg = (c < NCHUNK) ? deg_j : deg_i;
  int cc = (c < NCHUNK) ? c : c - NCHUNK;
  int t = threadIdx.x;
  int idx = cc * 256 + t;
  int v = (idx < NNODE) ? deg[idx] : 0;
  for (int off = 32; off; off >>= 1) v += __shfl_down(v, off, 64);
  __shared__ int wsum[4];
  if ((t & 63) == 0) wsum[t >> 6] = v;
  __syncthreads();
  if (t == 0) csum[c] = wsum[0] + wsum[1] + wsum[2] + wsum[3];
}

__global__ void chunkscan_kernel(const int* __restrict__ csum, int* __restrict__ coff) {
  int d = blockIdx.x;                    // 0 or 1
  const int* cs = csum + d * NCHUNK;
  int* co = coff + d * NCHUNK;
  int t = threadIdx.x, lane = t & 63, w = t >> 6;
  int v = (t < NCHUNK) ? cs[t] : 0;
  int x = v;
  for (int off = 1; off < 64; off <<= 1) {
    int y = __shfl_up(x, off, 64);
    if (lane >= off) x += y;
  }
  __shared__ int wt[4];
  if (lane == 63) wt[w] = x;
  __syncthreads();
  int add = 0;
  for (int k = 0; k < 4; ++k) if (k < w) add += wt[k];
  if (t < NCHUNK) co[t] = add + x - v;   // exclusive prefix
}

__global__ void localscan_kernel(const int* __restrict__ deg_j,
                                 const int* __restrict__ deg_i,
                                 const int* __restrict__ coff,
                                 int* __restrict__ rs_j, int* __restrict__ cur_j,
                                 int* __restrict__ rs_i, int* __restrict__ cur_i) {
  int c = blockIdx.x;
  bool dj = c < NCHUNK;
  const int* deg = dj ? deg_j : deg_i;
  int cc = dj ? c : c - NCHUNK;
  int* rs = dj ? rs_j : rs_i;
  int* cur = dj ? cur_j : cur_i;
  int base = coff[c];
  int t = threadIdx.x, lane = t & 63, w = t >> 6;
  int idx = cc * 256 + t;
  int v = (idx < NNODE) ? deg[idx] : 0;
  int x = v;
  for (int off = 1; off < 64; off <<= 1) {
    int y = __shfl_up(x, off, 64);
    if (lane >= off) x += y;
  }
  __shared__ int wt[4];
  if (lane == 63) wt[w] = x;
  __syncthreads();
  int add = 0;
  for (int k = 0; k < 4; ++k) if (k < w) add += wt[k];
  int ex = base + add + x - v;
  if (idx < NNODE) { rs[idx] = ex; cur[idx] = ex; }
}

// fill: one 16B record per edge: (src, eid, ts_bits, 0)
__global__ void fill_kernel(const int* __restrict__ src_g, const int* __restrict__ dst_g,
                            const float* __restrict__ t,
                            const int* __restrict__ src_gr, const int* __restrict__ dst_gr,
                            const float* __restrict__ t_r,
                            int* __restrict__ cur_j, int* __restrict__ cur_i,
                            int4* __restrict__ recP_j, int4* __restrict__ recP_i,
                            int E) {
  int i = blockIdx.x * 256 + threadIdx.x;
  if (i < E) {
    int pos = atomicAdd(&cur_j[dst_g[i]], 1);
    recP_j[pos] = make_int4(src_g[i], i, __float_as_int(t[i]), 0);
  } else if (i < 2 * E) {
    int k = i - E;
    int pos = atomicAdd(&cur_i[dst_gr[k]], 1);
    recP_i[pos] = make_int4(src_gr[k], k, __float_as_int(t_r[k]), 0);
  }
}

// ---------------- gather: mean-message + pack X row in A-fragment order ----------------
// packed k layout: [0,128)=mean src_mem, [128,256)=h*(deg>0), [256,320)=mean tenc,
// [320,384)=mean edge feat, [384,512)=h
__global__ __launch_bounds__(256) void gather_kernel(
    const float* __restrict__ si, const float* __restrict__ sj,
    const float* __restrict__ si_r, const float* __restrict__ sj_r,
    const float* __restrict__ e, const float* __restrict__ e_r,
    const int* __restrict__ rs_j, const int* __restrict__ rs_i,
    const int* __restrict__ deg_j, const int* __restrict__ deg_i,
    const int4* __restrict__ recP_j, const int4* __restrict__ recP_i,
    unsigned short* __restrict__ Xb) {
  __shared__ __align__(16) unsigned short rowbuf[4][512];
  int wid = threadIdx.x >> 6, lane = threadIdx.x & 63;
  int node = blockIdx.x * 4 + wid;                 // 0..99999
  bool user = node < NUSERS;
  int idx = user ? node : node - NUSERS;
  const float* smem = user ? si_r : si;
  const float* h    = user ? sj_r : sj;
  const float* ef   = user ? e_r : e;
  int start = __builtin_amdgcn_readfirstlane((user ? rs_i : rs_j)[idx]);
  int deg   = __builtin_amdgcn_readfirstlane((user ? deg_i : deg_j)[idx]);
  const int4* rec = user ? recP_i : recP_j;

  // freq[lane] = 10^(-9*lane/63) = exp(-lane * 9/63 * ln 10)
  float freq = __expf((float)lane * -0.3289407276f);
  float a0 = 0.f, a1 = 0.f, a2 = 0.f, a3 = 0.f;

  // 4-deep pipelined degree loop: 4 record loads then 12 independent feature loads
  for (int i = 0; i < deg; i += 4) {
    int i1 = (i + 1 < deg) ? i + 1 : deg - 1;
    int i2 = (i + 2 < deg) ? i + 2 : deg - 1;
    int i3 = (i + 3 < deg) ? i + 3 : deg - 1;
    int4 r0 = rec[start + i];
    int4 r1 = rec[start + i1];
    int4 r2 = rec[start + i2];
    int4 r3 = rec[start + i3];
    float w1 = (i + 1 < deg) ? 1.0f : 0.0f;
    float w2 = (i + 2 < deg) ? 1.0f : 0.0f;
    float w3 = (i + 3 < deg) ? 1.0f : 0.0f;

    float x00 = smem[(size_t)r0.x * 128 + lane];
    float x01 = smem[(size_t)r0.x * 128 + 64 + lane];
    float f0  = ef[(size_t)r0.y * 64 + lane];
    float x10 = smem[(size_t)r1.x * 128 + lane];
    float x11 = smem[(size_t)r1.x * 128 + 64 + lane];
    float f1  = ef[(size_t)r1.y * 64 + lane];
    float x20 = smem[(size_t)r2.x * 128 + lane];
    float x21 = smem[(size_t)r2.x * 128 + 64 + lane];
    float f2  = ef[(size_t)r2.y * 64 + lane];
    float x30 = smem[(size_t)r3.x * 128 + lane];
    float x31 = smem[(size_t)r3.x * 128 + 64 + lane];
    float f3  = ef[(size_t)r3.y * 64 + lane];

    float c0 = __cosf(__int_as_float(r0.z) * freq);
    float c1 = __cosf(__int_as_float(r1.z) * freq);
    float c2 = __cosf(__int_as_float(r2.z) * freq);
    float c3 = __cosf(__int_as_float(r3.z) * freq);

    a0 += x00 + w1 * x10 + w2 * x20 + w3 * x30;
    a1 += x01 + w1 * x11 + w2 * x21 + w3 * x31;
    a2 += c0  + w1 * c1  + w2 * c2  + w3 * c3;
    a3 += f0  + w1 * f1  + w2 * f2  + w3 * f3;
  }

  float invc = (deg > 0) ? 1.0f / (float)deg : 0.0f;
  float hz   = (deg > 0) ? 1.0f : 0.0f;
  float h0 = h[(size_t)idx * 128 + lane];
  float h1 = h[(size_t)idx * 128 + 64 + lane];

  unsigned short* rb = rowbuf[wid];
  rb[lane]        = f2bf(a0 * invc);
  rb[64  + lane]  = f2bf(a1 * invc);
  rb[128 + lane]  = f2bf(h0 * hz);
  rb[192 + lane]  = f2bf(h1 * hz);
  rb[256 + lane]  = f2bf(a2 * invc);
  rb[320 + lane]  = f2bf(a3 * invc);
  rb[384 + lane]  = f2bf(h0);
  rb[448 + lane]  = f2bf(h1);
  __syncthreads();

  // transpose-write in A-fragment order: lane owns k = lane*8 .. lane*8+8
  int rt = node >> 4, m = node & 15;
  int kt = lane >> 2, q = lane & 3;
  short8 vv = *(const short8*)(rb + lane * 8);
  *(short8*)(Xb + (((size_t)rt * 16 + kt) * 64 + q * 16 + m) * 8) = vv;
}

// ---------------- GEMM (100000 x 512) @ W''^T with fused GRU epilogue ----------------
__global__ __launch_bounds__(512, 2) void gemm_gru_kernel(
    const unsigned short* __restrict__ Xb,
    const unsigned short* __restrict__ Wb,
    const float* __restrict__ bb,
    const float* __restrict__ sj_r,
    const float* __restrict__ sj,
    float* __restrict__ out) {
  __shared__ __align__(16) unsigned short sB[32768];   // 64 KB
  int wid = threadIdx.x >> 6, lane = threadIdx.x & 63;
  int mtile = blockIdx.x * 8 + wid;
  bool valid = mtile < MTILES;
  int col16 = lane & 15, quad = lane >> 4;

  f32x4 acc[32];
#pragma unroll
  for (int t = 0; t < 32; ++t) acc[t] = (f32x4)0.0f;

  const unsigned short* Abase = Xb + (size_t)(valid ? mtile : 0) * 8192;

  for (int s = 0; s < 8; ++s) {
#pragma unroll
    for (int i = 0; i < 8; ++i) {
      int c = wid * 8 + i;
      int tt = c >> 1, kt = s * 2 + (c & 1);
      const unsigned short* g = Wb + ((size_t)(tt * 16 + kt) * 64 + lane) * 8;
      gload_lds16(g, sB + c * 512);
    }
    __syncthreads();
    if (valid) {
      short8 a0 = *(const short8*)(Abase + (size_t)(s * 2) * 512 + lane * 8);
      short8 a1 = *(const short8*)(Abase + (size_t)(s * 2 + 1) * 512 + lane * 8);
#pragma unroll
      for (int t = 0; t < 32; ++t) {
        short8 b0 = *(const short8*)(sB + (t * 2) * 512 + lane * 8);
        short8 b1 = *(const short8*)(sB + (t * 2 + 1) * 512 + lane * 8);
        acc[t] = __builtin_amdgcn_mfma_f32_16x16x32_bf16(a0, b0, acc[t], 0, 0, 0);
        acc[t] = __builtin_amdgcn_mfma_f32_16x16x32_bf16(a1, b1, acc[t], 0, 0, 0);
      }
    }
    __syncthreads();
  }

  if (!valid) return;
  int m0 = mtile * 16;
#pragma unroll
  for (int t = 0; t < 8; ++t) {
    int c = t * 16 + col16;
    float bbr = bb[c], bbz = bb[128 + c], bbn = bb[256 + c], bbh = bb[384 + c];
#pragma unroll
    for (int r = 0; r < 4; ++r) {
      int row = m0 + quad * 4 + r;
      float rp  = acc[t][r]      + bbr;
      float zp  = acc[t + 8][r]  + bbz;
      float inp = acc[t + 16][r] + bbn;
      float hnp = acc[t + 24][r] + bbh;
      float rg = 1.0f / (1.0f + __expf(-rp));
      float zg = 1.0f / (1.0f + __expf(-zp));
      float ng = tanhf(inp + rg * hnp);
      float hv = (row < NUSERS) ? sj_r[(size_t)row * 128 + c]
                                : sj[(size_t)(row - NUSERS) * 128 + c];
      out[(size_t)row * 128 + c] = (1.0f - zg) * ng + zg * hv;
    }
  }
}

extern "C" void kernel_launch(void* const* d_in, const int* in_sizes, int n_in,
                              void* d_out, int out_size, void* d_ws, size_t ws_size,
                              hipStream_t stream) {
  const float* si   = (const float*)d_in[0];
  const float* sj   = (const float*)d_in[1];
  const float* si_r = (const float*)d_in[2];
  const float* sj_r = (const float*)d_in[3];
  const float* t    = (const float*)d_in[4];
  const float* t_r  = (const float*)d_in[5];
  const float* e    = (const float*)d_in[6];
  const float* e_r  = (const float*)d_in[7];
  const float* w_ih = (const float*)d_in[8];
  const float* w_hh = (const float*)d_in[9];
  const float* b_ih = (const float*)d_in[10];
  const float* b_hh = (const float*)d_in[11];
  const int* src_g  = (const int*)d_in[12];
  const int* dst_g  = (const int*)d_in[13];
  const int* src_gr = (const int*)d_in[14];
  const int* dst_gr = (const int*)d_in[15];
  int E = in_sizes[4];

  // workspace layout (16B-aligned head first)
  unsigned short* Xb = (unsigned short*)d_ws;          // 51,200,000 shorts (102.4 MB)
  unsigned short* Wb = Xb + (size_t)MTILES * 8192;     // 262144 shorts
  float* bb   = (float*)(Wb + 262144);                 // 512
  int* deg_j  = (int*)(bb + 512);                      // 50000  (memset target, with deg_i)
  int* deg_i  = deg_j + NNODE;                         // 50000
  int* rs_j   = deg_i + NNODE;                         // 50000
  int* rs_i   = rs_j + NNODE;                          // 50000
  int* cur_j  = rs_i + NNODE;                          // 50000
  int* cur_i  = cur_j + NNODE;                         // 50000
  int* csum   = cur_i + NNODE;                         // 2*NCHUNK
  int* coff   = csum + 2 * NCHUNK;                     // 2*NCHUNK (ends 16B-aligned)
  int4* recP_j = (int4*)(coff + 2 * NCHUNK);           // E int4
  int4* recP_i = recP_j + E;                           // E int4

  hipMemsetAsync(deg_j, 0, 2 * NNODE * sizeof(int), stream);

  pack_w_kernel<<<(512 * 512) / 256, 256, 0, stream>>>(w_ih, w_hh, b_ih, b_hh, Wb, bb);

  int blks2E = (2 * E + 255) / 256;
  hist_kernel<<<blks2E, 256, 0, stream>>>(dst_g, dst_gr, deg_j, deg_i, E);
  chunksum_kernel<<<2 * NCHUNK, 256, 0, stream>>>(deg_j, deg_i, csum);
  chunkscan_kernel<<<2, 256, 0, stream>>>(csum, coff);
  localscan_kernel<<<2 * NCHUNK, 256, 0, stream>>>(deg_j, deg_i, coff, rs_j, cur_j, rs_i, cur_i);
  fill_kernel<<<blks2E, 256, 0, stream>>>(src_g, dst_g, t, src_gr, dst_gr, t_r,
                                          cur_j, cur_i, recP_j, recP_i, E);

  gather_kernel<<<NTOT / 4, 256, 0, stream>>>(si, sj, si_r, sj_r, e, e_r,
                                              rs_j, rs_i, deg_j, deg_i,
                                              recP_j, recP_i, Xb);

  float* out = (float*)d_out;
  gemm_gru_kernel<<<(MTILES + 7) / 8, 512, 0, stream>>>(Xb, Wb, bb, sj_r, sj, out);
}